// Round 15
// baseline (108.218 us; speedup 1.0000x reference)
//
#include <hip/hip_runtime.h>
#include <hip/hip_bf16.h>
#include <math.h>

#define BB 8
#define NN 2048
#define DD 1024
#define MTOT (BB * NN)
#define NT (NN / 128)            // 16 row/col tiles per batch
#define NTRI (NT * (NT + 1) / 2) // 136 triangular tiles
#define NJ 8                     // interpolation nodes
#define PAD 12                   // padded j-stride (16B-aligned, conflict-free b128)
#define QSCL 21.0f               // i8 quant scale (N(0,1) data; ±6.05 sigma, no clip)
#define INVQ (1.0f / (QSCL * QSCL))

typedef __attribute__((ext_vector_type(8))) short bf16x8_t;
typedef __attribute__((ext_vector_type(4))) float f32x4_t;
typedef __attribute__((ext_vector_type(4))) int i32x4_t;

__device__ __forceinline__ unsigned short f2bf(float f) {
  unsigned int u = __float_as_uint(f);
  unsigned int r = (u + 0x7FFFu + ((u >> 16) & 1u)) >> 16;
  return (unsigned short)r;
}

__device__ __forceinline__ void gload_lds16(const void* g, void* lds) {
  __builtin_amdgcn_global_load_lds(
      (const __attribute__((address_space(1))) void*)g,
      (__attribute__((address_space(3))) void*)lds, 16, 0, 0);
}

__device__ __forceinline__ float softplusf(float x) {
  return (x > 20.f) ? x : log1pf(expf(x));
}

__device__ __forceinline__ int q8(float x) {
  return __float2int_rn(fminf(fmaxf(x * QSCL, -127.f), 127.f)) & 0xff;
}

// hardware barrier + COMPILER memory fence (raw builtin is IntrNoMem -> LDS
// loads may be hoisted across it) — no vmcnt(0) drain like __syncthreads().
#define BARRIER() asm volatile("s_barrier" ::: "memory")

// K01: blocks [0,16384): per-row sumsq -> scale; data f32 -> bf16 Abuf + i8 Xq.
//      blocks [16384,17408): W2 top half [1024,1024] -> W2T bf16 transpose.
__global__ void k01_prep(const float* __restrict__ data, unsigned short* __restrict__ Abuf,
                         unsigned char* __restrict__ Xq, float* __restrict__ scale,
                         const float* __restrict__ W2, unsigned short* __restrict__ W2T) {
  const int t = threadIdx.x;
  if (blockIdx.x < MTOT) {
    const int row = blockIdx.x;
    float4 v = ((const float4*)(data + (size_t)row * DD))[t];
    float ss = v.x * v.x + v.y * v.y + v.z * v.z + v.w * v.w;
    #pragma unroll
    for (int i = 1; i < 64; i <<= 1) ss += __shfl_xor(ss, i);
    __shared__ float red[4];
    if ((t & 63) == 0) red[t >> 6] = ss;
    __syncthreads();
    if (t == 0) {
      float tot = red[0] + red[1] + red[2] + red[3];
      scale[row] = rsqrtf(fmaxf(tot, 1e-12f));
    }
    ushort4 o = make_ushort4(f2bf(v.x), f2bf(v.y), f2bf(v.z), f2bf(v.w));
    *(ushort4*)(&Abuf[(size_t)row * DD + t * 4]) = o;
    const int packed = q8(v.x) | (q8(v.y) << 8) | (q8(v.z) << 16) | (q8(v.w) << 24);
    *(int*)(&Xq[(size_t)row * DD + t * 4]) = packed;
  } else {
    __shared__ float tile[32][33];
    const int q = blockIdx.x - MTOT;
    const int nb = (q & 31) * 32;
    const int kb = (q >> 5) * 32;
    const int tx = t & 31, ty = t >> 5;
    #pragma unroll
    for (int i = 0; i < 32; i += 8)
      tile[ty + i][tx] = W2[(size_t)(kb + ty + i) * DD + nb + tx];
    __syncthreads();
    #pragma unroll
    for (int i = 0; i < 32; i += 8)
      W2T[(size_t)(nb + ty + i) * DD + kb + tx] = f2bf(tile[tx][ty + i]);
  }
}

// K2 (i8): triangular blocks rt<=ct of G = Xq@Xq^T / QSCL^2 per batch.
// K=128 staged per LDS tile (128B rows), 8 staging iters, 2x mfma_i32_16x16x64_i8.
// partial[row][slot]: row-side -> slot ct*2+wc ; col-side -> slot rt*2+wr.
__launch_bounds__(256)
__global__ void k2_sim(const unsigned char* __restrict__ Xq,
                       const float* __restrict__ scale,
                       float* __restrict__ partial) {
  __shared__ char As_s[128 * 128];
  __shared__ char Bs_s[128 * 128];
  const int t = threadIdx.x;
  const int w = t >> 6, l = t & 63;
  const int wr = w >> 1, wc = w & 1;

  const int nwg = BB * NTRI;  // 1088, %8==0
  const int logical = (blockIdx.x % 8) * (nwg / 8) + blockIdx.x / 8;
  const int b = logical / NTRI;
  int p = logical % NTRI;
  int rt = 0;
  while (p >= NT - rt) { p -= NT - rt; ++rt; }
  const int ct = rt + p;

  const size_t bbase = (size_t)b * NN * DD;
  const unsigned char* Ag = Xq + bbase + (size_t)rt * 128 * DD;
  const unsigned char* Bg = Xq + bbase + (size_t)ct * 128 * DD;
  const int lr = l >> 3;
  const int cg = (l & 7) ^ lr;  // swizzled global 16B-chunk (8 chunks per 128B row)
  i32x4_t acc[4][4] = {};

  for (int ks = 0; ks < DD / 128; ++ks) {  // 8 iterations, K=128 each
    #pragma unroll
    for (int i = 0; i < 4; ++i) {
      const int rl = i * 32 + w * 8 + lr;
      gload_lds16(Ag + (size_t)rl * DD + ks * 128 + cg * 16, &As_s[(i * 32 + w * 8) * 128]);
      gload_lds16(Bg + (size_t)rl * DD + ks * 128 + cg * 16, &Bs_s[(i * 32 + w * 8) * 128]);
    }
    __syncthreads();
    const i32x4_t* As = (const i32x4_t*)As_s;
    const i32x4_t* Bs = (const i32x4_t*)Bs_s;
    #pragma unroll
    for (int kk = 0; kk < 2; ++kk) {  // two K=64 MFMA steps per staged K=128
      const int ci = kk * 4 + (l >> 4);
      i32x4_t af[4], bq[4];
      #pragma unroll
      for (int m = 0; m < 4; ++m) {
        const int r = wr * 64 + m * 16 + (l & 15);
        af[m] = As[r * 8 + (ci ^ (r & 7))];
      }
      #pragma unroll
      for (int n = 0; n < 4; ++n) {
        const int r = wc * 64 + n * 16 + (l & 15);
        bq[n] = Bs[r * 8 + (ci ^ (r & 7))];
      }
      #pragma unroll
      for (int m = 0; m < 4; ++m)
        #pragma unroll
        for (int n = 0; n < 4; ++n)
          acc[m][n] = __builtin_amdgcn_mfma_i32_16x16x64_i8(af[m], bq[n], acc[m][n], 0, 0, 0);
    }
    __syncthreads();
  }

  const float* sb = scale + (size_t)b * NN;

  {  // row-side (1/QSCL^2 folded into scol)
    float scol[4];
    #pragma unroll
    for (int n = 0; n < 4; ++n)
      scol[n] = sb[ct * 128 + wc * 64 + n * 16 + (l & 15)] * INVQ;
    #pragma unroll
    for (int m = 0; m < 4; ++m) {
      #pragma unroll
      for (int r = 0; r < 4; ++r) {
        float x = 0.f;
        #pragma unroll
        for (int n = 0; n < 4; ++n)
          x += scol[n] * fmaxf((float)acc[m][n][r], 0.f);
        #pragma unroll
        for (int off = 1; off < 16; off <<= 1)
          x += __shfl_xor(x, off);
        if ((l & 15) == 0) {
          const int row = rt * 128 + wr * 64 + m * 16 + (l >> 4) * 4 + r;
          partial[((size_t)(b * NN + row)) * 32 + ct * 2 + wc] = x;
        }
      }
    }
  }

  if (rt != ct) {  // col-side (1/QSCL^2 folded into srow)
    float srow[4][4];
    #pragma unroll
    for (int m = 0; m < 4; ++m)
      #pragma unroll
      for (int r = 0; r < 4; ++r)
        srow[m][r] = sb[rt * 128 + wr * 64 + m * 16 + (l >> 4) * 4 + r] * INVQ;
    #pragma unroll
    for (int n = 0; n < 4; ++n) {
      float y = 0.f;
      #pragma unroll
      for (int m = 0; m < 4; ++m)
        #pragma unroll
        for (int r = 0; r < 4; ++r)
          y += srow[m][r] * fmaxf((float)acc[m][n][r], 0.f);
      y += __shfl_xor(y, 16);
      y += __shfl_xor(y, 32);
      if (l < 16) {
        const int crow = ct * 128 + wc * 64 + n * 16 + l;
        partial[((size_t)(b * NN + crow)) * 32 + rt * 2 + wr] = y;
      }
    }
  }
}

// K3a: c[row] = scale[row]*sum(partial[row][0..32)); per-block min/max -> mm[64][2]
__global__ void k3a_counter(const float* __restrict__ partial, const float* __restrict__ scale,
                            float* __restrict__ cbuf, float* __restrict__ mm) {
  const int row = blockIdx.x * 256 + threadIdx.x;
  const float4* pr = (const float4*)(partial + (size_t)row * 32);
  float c = 0.f;
  #pragma unroll
  for (int i = 0; i < 8; ++i) { float4 v = pr[i]; c += v.x + v.y + v.z + v.w; }
  c *= scale[row];
  cbuf[row] = c;
  float mn = c, mx = c;
  #pragma unroll
  for (int i = 1; i < 64; i <<= 1) {
    mn = fminf(mn, __shfl_xor(mn, i));
    mx = fmaxf(mx, __shfl_xor(mx, i));
  }
  __shared__ float smn[4], smx[4];
  if ((threadIdx.x & 63) == 0) { smn[threadIdx.x >> 6] = mn; smx[threadIdx.x >> 6] = mx; }
  __syncthreads();
  if (threadIdx.x == 0) {
    mn = fminf(fminf(smn[0], smn[1]), fminf(smn[2], smn[3]));
    mx = fmaxf(fmaxf(smx[0], smx[1]), fmaxf(smx[2], smx[3]));
    mm[blockIdx.x * 2] = mn;
    mm[blockIdx.x * 2 + 1] = mx;
  }
}

// K3b: reduce min/max over 64 blocks; compute 8 Chebyshev nodes + barycentric invD
__global__ void k3b_nodes(const float* __restrict__ mm, float* __restrict__ nd) {
  const int t = threadIdx.x;  // 64
  float mn = mm[t * 2], mx = mm[t * 2 + 1];
  #pragma unroll
  for (int i = 1; i < 64; i <<= 1) {
    mn = fminf(mn, __shfl_xor(mn, i));
    mx = fmaxf(mx, __shfl_xor(mx, i));
  }
  if (t == 0) {
    float mid = 0.5f * (mn + mx);
    float rad = 0.5f * (mx - mn);
    rad = fmaxf(rad, fmaxf(1e-3f, 1e-3f * fabsf(mid)));
    float c[NJ];
    #pragma unroll
    for (int j = 0; j < NJ; ++j)
      c[j] = mid + rad * cosf(3.14159265358979f * (2 * j + 1) / (2.0f * NJ));
    #pragma unroll
    for (int j = 0; j < NJ; ++j) nd[j] = c[j];
    #pragma unroll
    for (int j = 0; j < NJ; ++j) {
      float d = 1.f;
      #pragma unroll
      for (int i = 0; i < NJ; ++i)
        if (i != j) d *= (c[j] - c[i]);
      nd[NJ + j] = 1.f / d;
    }
  }
}

// K3cd: Fpart[s][j][n] = sum_{d in slice s} softplus(c_j*W1[d]+b1[d]) * W2[(1024+d)][n]
__global__ void k3cd_Fpart(const float* __restrict__ nd, const float* __restrict__ W1,
                           const float* __restrict__ b1, const float* __restrict__ W2,
                           float* __restrict__ Fpart) {
  const int s = blockIdx.x;   // 64
  const int t = threadIdx.x;  // 256
  __shared__ float Ssh[NJ * 16];
  if (t < NJ * 16) {
    const int j = t >> 4, dd = t & 15;
    const int d = s * 16 + dd;
    Ssh[j * 16 + dd] = softplusf(nd[j] * W1[d] + b1[d]);
  }
  __syncthreads();
  float4 acc[NJ] = {};
  for (int dd = 0; dd < 16; ++dd) {
    const int d = s * 16 + dd;
    float4 wv = ((const float4*)(W2 + (size_t)(DD + d) * DD))[t];
    #pragma unroll
    for (int j = 0; j < NJ; ++j) {
      float sv = Ssh[j * 16 + dd];
      acc[j].x += sv * wv.x; acc[j].y += sv * wv.y;
      acc[j].z += sv * wv.z; acc[j].w += sv * wv.w;
    }
  }
  #pragma unroll
  for (int j = 0; j < NJ; ++j)
    ((float4*)(Fpart + ((size_t)s * NJ + j) * DD))[t] = acc[j];
}

// K3e: F[j][n] = sum_s Fpart[s][j][n]   (L-matrix now computed inside k4)
__global__ void k3e_Fred(const float* __restrict__ Fpart, float* __restrict__ F) {
  const int gid = blockIdx.x * 256 + threadIdx.x;  // 8192
  float a = 0.f;
  for (int s = 0; s < 64; ++s) a += Fpart[((size_t)s * NJ) * DD + gid];
  F[gid] = a;
}

// K4 (round-9 best + in-prologue L): out = Abuf @ W2T^T + rank-8.
// 256x256 tile, BK=64, 8 waves (2M x 4N), 2-deep dbuf, 4 phases/K-tile,
// counted vmcnt(2), fenced barriers. L rows computed in-kernel from cbuf+nd
// (ordered vs epilogue by the K-loop barriers).
__launch_bounds__(512, 2)
__global__ void k4_out(const unsigned short* __restrict__ Abuf,
                       const unsigned short* __restrict__ W2T,
                       const float* __restrict__ cbuf,
                       const float* __restrict__ nd,
                       const float* __restrict__ F,
                       float* __restrict__ out) {
  __shared__ short As_s[2][256 * 64];
  __shared__ short Bs_s[2][256 * 64];
  __shared__ float Fsh[256 * PAD];  // [col 256][j 8, pad 12]
  __shared__ float Lsh[256 * PAD];  // [row 256][j 8, pad 12]
  const int t = threadIdx.x;
  const int w = t >> 6, l = t & 63;
  const int wr = w >> 2, wc = w & 3;   // 2M x 4N wave grid
  const int lr = l >> 3;
  const int cg = (l & 7) ^ lr;         // source-side chunk swizzle (rule #21 pair)

  // XCD-aware: 256 blocks, each XCD gets 8 consecutive rtiles x all 4 cts
  const int logical = ((int)blockIdx.x % 8) * 32 + (int)blockIdx.x / 8;
  const int rtile = logical >> 2;  // 0..63
  const int ct = logical & 3;      // 0..3

  const unsigned short* Ag = Abuf + (size_t)rtile * 256 * DD;
  const unsigned short* Bg = W2T + (size_t)ct * 256 * DD;

  // stage F slice; compute barycentric L rows in-kernel (t<256).
  #pragma unroll
  for (int q = 0; q < 4; ++q) {
    const int idx = q * 512 + t;  // 2048 = 256 x 8j
    const int j = idx & 7, e = idx >> 3;
    Fsh[e * PAD + j] = F[j * DD + ct * 256 + e];
  }
  if (t < 256) {
    const float c = cbuf[rtile * 256 + t];
    float ndv[NJ], inv[NJ];
    #pragma unroll
    for (int j = 0; j < NJ; ++j) { ndv[j] = nd[j]; inv[j] = nd[NJ + j]; }
    #pragma unroll
    for (int j = 0; j < NJ; ++j) {
      float prod = inv[j];
      #pragma unroll
      for (int i = 0; i < NJ; ++i)
        if (i != j) prod *= (c - ndv[i]);
      Lsh[t * PAD + j] = prod;
    }
  }

  f32x4_t acc[8][4] = {};

  #define STG(XS, Xg, buf, kt, h)                                              \
    _Pragma("unroll") for (int i = 0; i < 2; ++i) {                            \
      const int rloc = (h) * 128 + i * 64 + w * 8;                             \
      gload_lds16(Xg + (size_t)(rloc + lr) * DD + (kt) * 64 + cg * 8,          \
                  &XS[buf][rloc * 64]);                                        \
    }

  // prologue: stage K-tile 0 (8 loads/thread)
  STG(As_s, Ag, 0, 0, 0); STG(As_s, Ag, 0, 0, 1);
  STG(Bs_s, Bg, 0, 0, 0); STG(Bs_s, Bg, 0, 0, 1);

  bf16x8_t bq[4][2];

  for (int kt = 0; kt < 16; ++kt) {
    const int rd = kt & 1, nx = rd ^ 1;
    const bf16x8_t* As = (const bf16x8_t*)&As_s[rd][0];
    const bf16x8_t* Bs = (const bf16x8_t*)&Bs_s[rd][0];

    // ---- phase 0
    if (kt < 15) {
      STG(As_s, Ag, nx, kt + 1, 0);
      asm volatile("s_waitcnt vmcnt(2)" ::: "memory");
    } else {
      asm volatile("s_waitcnt vmcnt(0)" ::: "memory");
    }
    BARRIER();
    __builtin_amdgcn_sched_barrier(0);
    #pragma unroll
    for (int n = 0; n < 4; ++n) {  // B frags: live across all 4 phases
      const int r = wc * 64 + n * 16 + (l & 15);
      #pragma unroll
      for (int kk = 0; kk < 2; ++kk)
        bq[n][kk] = Bs[r * 8 + ((kk * 4 + (l >> 4)) ^ (r & 7))];
    }
    {
      bf16x8_t af[2][2];
      #pragma unroll
      for (int mi = 0; mi < 2; ++mi) {
        const int r = wr * 128 + mi * 16 + (l & 15);
        #pragma unroll
        for (int kk = 0; kk < 2; ++kk)
          af[mi][kk] = As[r * 8 + ((kk * 4 + (l >> 4)) ^ (r & 7))];
      }
      asm volatile("s_waitcnt lgkmcnt(0)" ::: "memory");
      __builtin_amdgcn_sched_barrier(0);
      __builtin_amdgcn_s_setprio(1);
      #pragma unroll
      for (int mi = 0; mi < 2; ++mi)
        #pragma unroll
        for (int n = 0; n < 4; ++n)
          #pragma unroll
          for (int kk = 0; kk < 2; ++kk)
            acc[mi][n] = __builtin_amdgcn_mfma_f32_16x16x32_bf16(
                af[mi][kk], bq[n][kk], acc[mi][n], 0, 0, 0);
      __builtin_amdgcn_s_setprio(0);
    }
    BARRIER();

    // ---- phases 1..3
    #pragma unroll
    for (int p = 1; p < 4; ++p) {
      bf16x8_t af[2][2];
      #pragma unroll
      for (int mi = 0; mi < 2; ++mi) {
        const int r = wr * 128 + (2 * p + mi) * 16 + (l & 15);
        #pragma unroll
        for (int kk = 0; kk < 2; ++kk)
          af[mi][kk] = As[r * 8 + ((kk * 4 + (l >> 4)) ^ (r & 7))];
      }
      if (kt < 15) {
        if (p == 1) { STG(As_s, Ag, nx, kt + 1, 1); }
        else if (p == 2) { STG(Bs_s, Bg, nx, kt + 1, 0); }
        else { STG(Bs_s, Bg, nx, kt + 1, 1); }
      }
      BARRIER();
      asm volatile("s_waitcnt lgkmcnt(0)" ::: "memory");
      __builtin_amdgcn_sched_barrier(0);
      __builtin_amdgcn_s_setprio(1);
      #pragma unroll
      for (int mi = 0; mi < 2; ++mi)
        #pragma unroll
        for (int n = 0; n < 4; ++n)
          #pragma unroll
          for (int kk = 0; kk < 2; ++kk)
            acc[2 * p + mi][n] = __builtin_amdgcn_mfma_f32_16x16x32_bf16(
                af[mi][kk], bq[n][kk], acc[2 * p + mi][n], 0, 0, 0);
      __builtin_amdgcn_s_setprio(0);
      BARRIER();
    }
  }
  #undef STG

  // epilogue: += rank-8 (Lsh/Fsh padded, conflict-free b128 reads)
  #pragma unroll
  for (int m = 0; m < 8; ++m)
    #pragma unroll
    for (int r = 0; r < 4; ++r) {
      const int rl_ = wr * 128 + m * 16 + (l >> 4) * 4 + r;
      const f32x4_t L0 = *(const f32x4_t*)&Lsh[rl_ * PAD];
      const f32x4_t L1 = *(const f32x4_t*)&Lsh[rl_ * PAD + 4];
      #pragma unroll
      for (int n = 0; n < 4; ++n) {
        const int cl_ = wc * 64 + n * 16 + (l & 15);
        const f32x4_t F0 = *(const f32x4_t*)&Fsh[cl_ * PAD];
        const f32x4_t F1 = *(const f32x4_t*)&Fsh[cl_ * PAD + 4];
        const float add = L0[0] * F0[0] + L0[1] * F0[1] + L0[2] * F0[2] + L0[3] * F0[3] +
                          L1[0] * F1[0] + L1[1] * F1[1] + L1[2] * F1[2] + L1[3] * F1[3];
        out[(size_t)(rtile * 256 + rl_) * DD + ct * 256 + cl_] = acc[m][n][r] + add;
      }
    }
}

extern "C" void kernel_launch(void* const* d_in, const int* in_sizes, int n_in,
                              void* d_out, int out_size, void* d_ws, size_t ws_size,
                              hipStream_t stream) {
  const float* data = (const float*)d_in[0];
  const float* W1 = (const float*)d_in[1];
  const float* b1 = (const float*)d_in[2];
  const float* W2 = (const float*)d_in[3];
  float* out = (float*)d_out;

  char* ws = (char*)d_ws;
  unsigned short* Abuf = (unsigned short*)(ws + 0);          // 33554432 B
  unsigned short* W2T = (unsigned short*)(ws + 33554432);    //  2097152 B
  float* partial = (float*)(ws + 35651584);                  //  2097152 B
  float* scale = (float*)(ws + 37748736);                    //    65536 B
  float* cbuf = (float*)(ws + 37814272);                     //    65536 B
  float* mm = (float*)(ws + 37879808);                       //      512 B
  float* nd = (float*)(ws + 37880320);                       //      256 B
  float* F = (float*)(ws + 37913344);                        //    32768 B
  float* Fpart = (float*)(ws + 37946112);                    //  2097152 B
  unsigned char* Xq = (unsigned char*)(ws + 40567552);       // 16777216 B

  hipLaunchKernelGGL(k01_prep, dim3(MTOT + 1024), dim3(256), 0, stream,
                     data, Abuf, Xq, scale, W2, W2T);
  hipLaunchKernelGGL(k2_sim, dim3(BB * NTRI), dim3(256), 0, stream, Xq, scale, partial);
  hipLaunchKernelGGL(k3a_counter, dim3(MTOT / 256), dim3(256), 0, stream, partial, scale, cbuf, mm);
  hipLaunchKernelGGL(k3b_nodes, dim3(1), dim3(64), 0, stream, mm, nd);
  hipLaunchKernelGGL(k3cd_Fpart, dim3(64), dim3(256), 0, stream, nd, W1, b1, W2, Fpart);
  hipLaunchKernelGGL(k3e_Fred, dim3(32), dim3(256), 0, stream, Fpart, F);
  hipLaunchKernelGGL(k4_out, dim3(64 * 4), dim3(512), 0, stream,
                     Abuf, W2T, cbuf, nd, F, out);
}

// Round 16
// 107.680 us; speedup vs baseline: 1.0050x; 1.0050x over previous
//
#include <hip/hip_runtime.h>
#include <hip/hip_bf16.h>
#include <math.h>

#define BB 8
#define NN 2048
#define DD 1024
#define MTOT (BB * NN)
#define NT (NN / 128)            // 16 row/col tiles per batch
#define NTRI (NT * (NT + 1) / 2) // 136 triangular tiles
#define NJ 8                     // interpolation nodes
#define PAD 12                   // padded j-stride (16B-aligned, conflict-free b128)
#define QSCL 21.0f               // i8 quant scale (N(0,1) data; ±6.05 sigma, no clip)
#define INVQ (1.0f / (QSCL * QSCL))

typedef __attribute__((ext_vector_type(8))) short bf16x8_t;
typedef __attribute__((ext_vector_type(4))) float f32x4_t;
typedef __attribute__((ext_vector_type(4))) int i32x4_t;

__device__ __forceinline__ unsigned short f2bf(float f) {
  unsigned int u = __float_as_uint(f);
  unsigned int r = (u + 0x7FFFu + ((u >> 16) & 1u)) >> 16;
  return (unsigned short)r;
}

__device__ __forceinline__ void gload_lds16(const void* g, void* lds) {
  __builtin_amdgcn_global_load_lds(
      (const __attribute__((address_space(1))) void*)g,
      (__attribute__((address_space(3))) void*)lds, 16, 0, 0);
}

__device__ __forceinline__ float softplusf(float x) {
  return (x > 20.f) ? x : log1pf(expf(x));
}

__device__ __forceinline__ int q8(float x) {
  return __float2int_rn(fminf(fmaxf(x * QSCL, -127.f), 127.f)) & 0xff;
}

// hardware barrier + COMPILER memory fence (raw builtin is IntrNoMem -> LDS
// loads may be hoisted across it) — no vmcnt(0) drain like __syncthreads().
#define BARRIER() asm volatile("s_barrier" ::: "memory")

// K01: blocks [0,16384): per-row sumsq -> scale; data f32 -> bf16 Abuf + i8 Xq.
//      blocks [16384,17408): W2 top half [1024,1024] -> W2T bf16 transpose.
__global__ void k01_prep(const float* __restrict__ data, unsigned short* __restrict__ Abuf,
                         unsigned char* __restrict__ Xq, float* __restrict__ scale,
                         const float* __restrict__ W2, unsigned short* __restrict__ W2T) {
  const int t = threadIdx.x;
  if (blockIdx.x < MTOT) {
    const int row = blockIdx.x;
    float4 v = ((const float4*)(data + (size_t)row * DD))[t];
    float ss = v.x * v.x + v.y * v.y + v.z * v.z + v.w * v.w;
    #pragma unroll
    for (int i = 1; i < 64; i <<= 1) ss += __shfl_xor(ss, i);
    __shared__ float red[4];
    if ((t & 63) == 0) red[t >> 6] = ss;
    __syncthreads();
    if (t == 0) {
      float tot = red[0] + red[1] + red[2] + red[3];
      scale[row] = rsqrtf(fmaxf(tot, 1e-12f));
    }
    ushort4 o = make_ushort4(f2bf(v.x), f2bf(v.y), f2bf(v.z), f2bf(v.w));
    *(ushort4*)(&Abuf[(size_t)row * DD + t * 4]) = o;
    const int packed = q8(v.x) | (q8(v.y) << 8) | (q8(v.z) << 16) | (q8(v.w) << 24);
    *(int*)(&Xq[(size_t)row * DD + t * 4]) = packed;
  } else {
    __shared__ float tile[32][33];
    const int q = blockIdx.x - MTOT;
    const int nb = (q & 31) * 32;
    const int kb = (q >> 5) * 32;
    const int tx = t & 31, ty = t >> 5;
    #pragma unroll
    for (int i = 0; i < 32; i += 8)
      tile[ty + i][tx] = W2[(size_t)(kb + ty + i) * DD + nb + tx];
    __syncthreads();
    #pragma unroll
    for (int i = 0; i < 32; i += 8)
      W2T[(size_t)(nb + ty + i) * DD + kb + tx] = f2bf(tile[tx][ty + i]);
  }
}

// K2 (i8): triangular blocks rt<=ct of G = Xq@Xq^T / QSCL^2 per batch.
// K=128 staged per LDS tile (128B rows), 8 staging iters, 2x mfma_i32_16x16x64_i8.
// partial[row][slot]: row-side -> slot ct*2+wc ; col-side -> slot rt*2+wr.
__launch_bounds__(256)
__global__ void k2_sim(const unsigned char* __restrict__ Xq,
                       const float* __restrict__ scale,
                       float* __restrict__ partial) {
  __shared__ char As_s[128 * 128];
  __shared__ char Bs_s[128 * 128];
  const int t = threadIdx.x;
  const int w = t >> 6, l = t & 63;
  const int wr = w >> 1, wc = w & 1;

  const int nwg = BB * NTRI;  // 1088, %8==0
  const int logical = (blockIdx.x % 8) * (nwg / 8) + blockIdx.x / 8;
  const int b = logical / NTRI;
  int p = logical % NTRI;
  int rt = 0;
  while (p >= NT - rt) { p -= NT - rt; ++rt; }
  const int ct = rt + p;

  const size_t bbase = (size_t)b * NN * DD;
  const unsigned char* Ag = Xq + bbase + (size_t)rt * 128 * DD;
  const unsigned char* Bg = Xq + bbase + (size_t)ct * 128 * DD;
  const int lr = l >> 3;
  const int cg = (l & 7) ^ lr;  // swizzled global 16B-chunk (8 chunks per 128B row)
  i32x4_t acc[4][4] = {};

  for (int ks = 0; ks < DD / 128; ++ks) {  // 8 iterations, K=128 each
    #pragma unroll
    for (int i = 0; i < 4; ++i) {
      const int rl = i * 32 + w * 8 + lr;
      gload_lds16(Ag + (size_t)rl * DD + ks * 128 + cg * 16, &As_s[(i * 32 + w * 8) * 128]);
      gload_lds16(Bg + (size_t)rl * DD + ks * 128 + cg * 16, &Bs_s[(i * 32 + w * 8) * 128]);
    }
    __syncthreads();
    const i32x4_t* As = (const i32x4_t*)As_s;
    const i32x4_t* Bs = (const i32x4_t*)Bs_s;
    #pragma unroll
    for (int kk = 0; kk < 2; ++kk) {  // two K=64 MFMA steps per staged K=128
      const int ci = kk * 4 + (l >> 4);
      i32x4_t af[4], bq[4];
      #pragma unroll
      for (int m = 0; m < 4; ++m) {
        const int r = wr * 64 + m * 16 + (l & 15);
        af[m] = As[r * 8 + (ci ^ (r & 7))];
      }
      #pragma unroll
      for (int n = 0; n < 4; ++n) {
        const int r = wc * 64 + n * 16 + (l & 15);
        bq[n] = Bs[r * 8 + (ci ^ (r & 7))];
      }
      #pragma unroll
      for (int m = 0; m < 4; ++m)
        #pragma unroll
        for (int n = 0; n < 4; ++n)
          acc[m][n] = __builtin_amdgcn_mfma_i32_16x16x64_i8(af[m], bq[n], acc[m][n], 0, 0, 0);
    }
    __syncthreads();
  }

  const float* sb = scale + (size_t)b * NN;

  {  // row-side (1/QSCL^2 folded into scol)
    float scol[4];
    #pragma unroll
    for (int n = 0; n < 4; ++n)
      scol[n] = sb[ct * 128 + wc * 64 + n * 16 + (l & 15)] * INVQ;
    #pragma unroll
    for (int m = 0; m < 4; ++m) {
      #pragma unroll
      for (int r = 0; r < 4; ++r) {
        float x = 0.f;
        #pragma unroll
        for (int n = 0; n < 4; ++n)
          x += scol[n] * fmaxf((float)acc[m][n][r], 0.f);
        #pragma unroll
        for (int off = 1; off < 16; off <<= 1)
          x += __shfl_xor(x, off);
        if ((l & 15) == 0) {
          const int row = rt * 128 + wr * 64 + m * 16 + (l >> 4) * 4 + r;
          partial[((size_t)(b * NN + row)) * 32 + ct * 2 + wc] = x;
        }
      }
    }
  }

  if (rt != ct) {  // col-side (1/QSCL^2 folded into srow)
    float srow[4][4];
    #pragma unroll
    for (int m = 0; m < 4; ++m)
      #pragma unroll
      for (int r = 0; r < 4; ++r)
        srow[m][r] = sb[rt * 128 + wr * 64 + m * 16 + (l >> 4) * 4 + r] * INVQ;
    #pragma unroll
    for (int n = 0; n < 4; ++n) {
      float y = 0.f;
      #pragma unroll
      for (int m = 0; m < 4; ++m)
        #pragma unroll
        for (int r = 0; r < 4; ++r)
          y += srow[m][r] * fmaxf((float)acc[m][n][r], 0.f);
      y += __shfl_xor(y, 16);
      y += __shfl_xor(y, 32);
      if (l < 16) {
        const int crow = ct * 128 + wc * 64 + n * 16 + l;
        partial[((size_t)(b * NN + crow)) * 32 + rt * 2 + wr] = y;
      }
    }
  }
}

// K3a: c[row] = scale[row]*sum(partial[row][0..32)); per-block min/max -> mm[64][2]
__global__ void k3a_counter(const float* __restrict__ partial, const float* __restrict__ scale,
                            float* __restrict__ cbuf, float* __restrict__ mm) {
  const int row = blockIdx.x * 256 + threadIdx.x;
  const float4* pr = (const float4*)(partial + (size_t)row * 32);
  float c = 0.f;
  #pragma unroll
  for (int i = 0; i < 8; ++i) { float4 v = pr[i]; c += v.x + v.y + v.z + v.w; }
  c *= scale[row];
  cbuf[row] = c;
  float mn = c, mx = c;
  #pragma unroll
  for (int i = 1; i < 64; i <<= 1) {
    mn = fminf(mn, __shfl_xor(mn, i));
    mx = fmaxf(mx, __shfl_xor(mx, i));
  }
  __shared__ float smn[4], smx[4];
  if ((threadIdx.x & 63) == 0) { smn[threadIdx.x >> 6] = mn; smx[threadIdx.x >> 6] = mx; }
  __syncthreads();
  if (threadIdx.x == 0) {
    mn = fminf(fminf(smn[0], smn[1]), fminf(smn[2], smn[3]));
    mx = fmaxf(fmaxf(smx[0], smx[1]), fmaxf(smx[2], smx[3]));
    mm[blockIdx.x * 2] = mn;
    mm[blockIdx.x * 2 + 1] = mx;
  }
}

// K3b: reduce min/max over 64 blocks; compute 8 Chebyshev nodes + barycentric invD
__global__ void k3b_nodes(const float* __restrict__ mm, float* __restrict__ nd) {
  const int t = threadIdx.x;  // 64
  float mn = mm[t * 2], mx = mm[t * 2 + 1];
  #pragma unroll
  for (int i = 1; i < 64; i <<= 1) {
    mn = fminf(mn, __shfl_xor(mn, i));
    mx = fmaxf(mx, __shfl_xor(mx, i));
  }
  if (t == 0) {
    float mid = 0.5f * (mn + mx);
    float rad = 0.5f * (mx - mn);
    rad = fmaxf(rad, fmaxf(1e-3f, 1e-3f * fabsf(mid)));
    float c[NJ];
    #pragma unroll
    for (int j = 0; j < NJ; ++j)
      c[j] = mid + rad * cosf(3.14159265358979f * (2 * j + 1) / (2.0f * NJ));
    #pragma unroll
    for (int j = 0; j < NJ; ++j) nd[j] = c[j];
    #pragma unroll
    for (int j = 0; j < NJ; ++j) {
      float d = 1.f;
      #pragma unroll
      for (int i = 0; i < NJ; ++i)
        if (i != j) d *= (c[j] - c[i]);
      nd[NJ + j] = 1.f / d;
    }
  }
}

// K3cd: Fpart[s][j][n] = sum_{d in slice s} softplus(c_j*W1[d]+b1[d]) * W2[(1024+d)][n]
__global__ void k3cd_Fpart(const float* __restrict__ nd, const float* __restrict__ W1,
                           const float* __restrict__ b1, const float* __restrict__ W2,
                           float* __restrict__ Fpart) {
  const int s = blockIdx.x;   // 64
  const int t = threadIdx.x;  // 256
  __shared__ float Ssh[NJ * 16];
  if (t < NJ * 16) {
    const int j = t >> 4, dd = t & 15;
    const int d = s * 16 + dd;
    Ssh[j * 16 + dd] = softplusf(nd[j] * W1[d] + b1[d]);
  }
  __syncthreads();
  float4 acc[NJ] = {};
  for (int dd = 0; dd < 16; ++dd) {
    const int d = s * 16 + dd;
    float4 wv = ((const float4*)(W2 + (size_t)(DD + d) * DD))[t];
    #pragma unroll
    for (int j = 0; j < NJ; ++j) {
      float sv = Ssh[j * 16 + dd];
      acc[j].x += sv * wv.x; acc[j].y += sv * wv.y;
      acc[j].z += sv * wv.z; acc[j].w += sv * wv.w;
    }
  }
  #pragma unroll
  for (int j = 0; j < NJ; ++j)
    ((float4*)(Fpart + ((size_t)s * NJ + j) * DD))[t] = acc[j];
}

// K3e: F[j][n] = sum_s Fpart[s][j][n]   (L-matrix computed inside k4)
__global__ void k3e_Fred(const float* __restrict__ Fpart, float* __restrict__ F) {
  const int gid = blockIdx.x * 256 + threadIdx.x;  // 8192
  float a = 0.f;
  for (int s = 0; s < 64; ++s) a += Fpart[((size_t)s * NJ) * DD + gid];
  F[gid] = a;
}

// K4: out = Abuf @ W2T^T + rank-8. 256x256 tile, BK=64, 8 waves (2M x 4N),
// 2-deep dbuf, 4 phases/K-tile, counted vmcnt(2), fenced barriers.
// UN-PINNED phase interiors: fragment reads are compiler-generated LDS loads —
// ordered across BARRIER() by its memory clobber, with automatic fine-grained
// lgkmcnt interleave into the MFMAs (no manual lgkmcnt(0)/sched_barrier pin).
__launch_bounds__(512, 2)
__global__ void k4_out(const unsigned short* __restrict__ Abuf,
                       const unsigned short* __restrict__ W2T,
                       const float* __restrict__ cbuf,
                       const float* __restrict__ nd,
                       const float* __restrict__ F,
                       float* __restrict__ out) {
  __shared__ short As_s[2][256 * 64];
  __shared__ short Bs_s[2][256 * 64];
  __shared__ float Fsh[256 * PAD];  // [col 256][j 8, pad 12]
  __shared__ float Lsh[256 * PAD];  // [row 256][j 8, pad 12]
  const int t = threadIdx.x;
  const int w = t >> 6, l = t & 63;
  const int wr = w >> 2, wc = w & 3;   // 2M x 4N wave grid
  const int lr = l >> 3;
  const int cg = (l & 7) ^ lr;         // source-side chunk swizzle (rule #21 pair)

  // XCD-aware: 256 blocks, each XCD gets 8 consecutive rtiles x all 4 cts
  const int logical = ((int)blockIdx.x % 8) * 32 + (int)blockIdx.x / 8;
  const int rtile = logical >> 2;  // 0..63
  const int ct = logical & 3;      // 0..3

  const unsigned short* Ag = Abuf + (size_t)rtile * 256 * DD;
  const unsigned short* Bg = W2T + (size_t)ct * 256 * DD;

  // stage F slice; compute barycentric L rows in-kernel (t<256).
  #pragma unroll
  for (int q = 0; q < 4; ++q) {
    const int idx = q * 512 + t;  // 2048 = 256 x 8j
    const int j = idx & 7, e = idx >> 3;
    Fsh[e * PAD + j] = F[j * DD + ct * 256 + e];
  }
  if (t < 256) {
    const float c = cbuf[rtile * 256 + t];
    float ndv[NJ], inv[NJ];
    #pragma unroll
    for (int j = 0; j < NJ; ++j) { ndv[j] = nd[j]; inv[j] = nd[NJ + j]; }
    #pragma unroll
    for (int j = 0; j < NJ; ++j) {
      float prod = inv[j];
      #pragma unroll
      for (int i = 0; i < NJ; ++i)
        if (i != j) prod *= (c - ndv[i]);
      Lsh[t * PAD + j] = prod;
    }
  }

  f32x4_t acc[8][4] = {};

  #define STG(XS, Xg, buf, kt, h)                                              \
    _Pragma("unroll") for (int i = 0; i < 2; ++i) {                            \
      const int rloc = (h) * 128 + i * 64 + w * 8;                             \
      gload_lds16(Xg + (size_t)(rloc + lr) * DD + (kt) * 64 + cg * 8,          \
                  &XS[buf][rloc * 64]);                                        \
    }

  // prologue: stage K-tile 0 (8 loads/thread)
  STG(As_s, Ag, 0, 0, 0); STG(As_s, Ag, 0, 0, 1);
  STG(Bs_s, Bg, 0, 0, 0); STG(Bs_s, Bg, 0, 0, 1);

  bf16x8_t bq[4][2];

  for (int kt = 0; kt < 16; ++kt) {
    const int rd = kt & 1, nx = rd ^ 1;
    const bf16x8_t* As = (const bf16x8_t*)&As_s[rd][0];
    const bf16x8_t* Bs = (const bf16x8_t*)&Bs_s[rd][0];

    // ---- phase 0
    if (kt < 15) {
      STG(As_s, Ag, nx, kt + 1, 0);
      asm volatile("s_waitcnt vmcnt(2)" ::: "memory");
    } else {
      asm volatile("s_waitcnt vmcnt(0)" ::: "memory");
    }
    BARRIER();
    #pragma unroll
    for (int n = 0; n < 4; ++n) {  // B frags: live across all 4 phases
      const int r = wc * 64 + n * 16 + (l & 15);
      #pragma unroll
      for (int kk = 0; kk < 2; ++kk)
        bq[n][kk] = Bs[r * 8 + ((kk * 4 + (l >> 4)) ^ (r & 7))];
    }
    {
      bf16x8_t af[2][2];
      #pragma unroll
      for (int mi = 0; mi < 2; ++mi) {
        const int r = wr * 128 + mi * 16 + (l & 15);
        #pragma unroll
        for (int kk = 0; kk < 2; ++kk)
          af[mi][kk] = As[r * 8 + ((kk * 4 + (l >> 4)) ^ (r & 7))];
      }
      __builtin_amdgcn_s_setprio(1);
      #pragma unroll
      for (int mi = 0; mi < 2; ++mi)
        #pragma unroll
        for (int n = 0; n < 4; ++n)
          #pragma unroll
          for (int kk = 0; kk < 2; ++kk)
            acc[mi][n] = __builtin_amdgcn_mfma_f32_16x16x32_bf16(
                af[mi][kk], bq[n][kk], acc[mi][n], 0, 0, 0);
      __builtin_amdgcn_s_setprio(0);
    }
    BARRIER();

    // ---- phases 1..3
    #pragma unroll
    for (int p = 1; p < 4; ++p) {
      bf16x8_t af[2][2];
      #pragma unroll
      for (int mi = 0; mi < 2; ++mi) {
        const int r = wr * 128 + (2 * p + mi) * 16 + (l & 15);
        #pragma unroll
        for (int kk = 0; kk < 2; ++kk)
          af[mi][kk] = As[r * 8 + ((kk * 4 + (l >> 4)) ^ (r & 7))];
      }
      if (kt < 15) {
        if (p == 1) { STG(As_s, Ag, nx, kt + 1, 1); }
        else if (p == 2) { STG(Bs_s, Bg, nx, kt + 1, 0); }
        else { STG(Bs_s, Bg, nx, kt + 1, 1); }
      }
      BARRIER();
      __builtin_amdgcn_s_setprio(1);
      #pragma unroll
      for (int mi = 0; mi < 2; ++mi)
        #pragma unroll
        for (int n = 0; n < 4; ++n)
          #pragma unroll
          for (int kk = 0; kk < 2; ++kk)
            acc[2 * p + mi][n] = __builtin_amdgcn_mfma_f32_16x16x32_bf16(
                af[mi][kk], bq[n][kk], acc[2 * p + mi][n], 0, 0, 0);
      __builtin_amdgcn_s_setprio(0);
      BARRIER();
    }
  }
  #undef STG

  // epilogue: += rank-8 (Lsh/Fsh padded, conflict-free b128 reads)
  #pragma unroll
  for (int m = 0; m < 8; ++m)
    #pragma unroll
    for (int r = 0; r < 4; ++r) {
      const int rl_ = wr * 128 + m * 16 + (l >> 4) * 4 + r;
      const f32x4_t L0 = *(const f32x4_t*)&Lsh[rl_ * PAD];
      const f32x4_t L1 = *(const f32x4_t*)&Lsh[rl_ * PAD + 4];
      #pragma unroll
      for (int n = 0; n < 4; ++n) {
        const int cl_ = wc * 64 + n * 16 + (l & 15);
        const f32x4_t F0 = *(const f32x4_t*)&Fsh[cl_ * PAD];
        const f32x4_t F1 = *(const f32x4_t*)&Fsh[cl_ * PAD + 4];
        const float add = L0[0] * F0[0] + L0[1] * F0[1] + L0[2] * F0[2] + L0[3] * F0[3] +
                          L1[0] * F1[0] + L1[1] * F1[1] + L1[2] * F1[2] + L1[3] * F1[3];
        out[(size_t)(rtile * 256 + rl_) * DD + ct * 256 + cl_] = acc[m][n][r] + add;
      }
    }
}

extern "C" void kernel_launch(void* const* d_in, const int* in_sizes, int n_in,
                              void* d_out, int out_size, void* d_ws, size_t ws_size,
                              hipStream_t stream) {
  const float* data = (const float*)d_in[0];
  const float* W1 = (const float*)d_in[1];
  const float* b1 = (const float*)d_in[2];
  const float* W2 = (const float*)d_in[3];
  float* out = (float*)d_out;

  char* ws = (char*)d_ws;
  unsigned short* Abuf = (unsigned short*)(ws + 0);          // 33554432 B
  unsigned short* W2T = (unsigned short*)(ws + 33554432);    //  2097152 B
  float* partial = (float*)(ws + 35651584);                  //  2097152 B
  float* scale = (float*)(ws + 37748736);                    //    65536 B
  float* cbuf = (float*)(ws + 37814272);                     //    65536 B
  float* mm = (float*)(ws + 37879808);                       //      512 B
  float* nd = (float*)(ws + 37880320);                       //      256 B
  float* F = (float*)(ws + 37913344);                        //    32768 B
  float* Fpart = (float*)(ws + 37946112);                    //  2097152 B
  unsigned char* Xq = (unsigned char*)(ws + 40567552);       // 16777216 B

  hipLaunchKernelGGL(k01_prep, dim3(MTOT + 1024), dim3(256), 0, stream,
                     data, Abuf, Xq, scale, W2, W2T);
  hipLaunchKernelGGL(k2_sim, dim3(BB * NTRI), dim3(256), 0, stream, Xq, scale, partial);
  hipLaunchKernelGGL(k3a_counter, dim3(MTOT / 256), dim3(256), 0, stream, partial, scale, cbuf, mm);
  hipLaunchKernelGGL(k3b_nodes, dim3(1), dim3(64), 0, stream, mm, nd);
  hipLaunchKernelGGL(k3cd_Fpart, dim3(64), dim3(256), 0, stream, nd, W1, b1, W2, Fpart);
  hipLaunchKernelGGL(k3e_Fred, dim3(32), dim3(256), 0, stream, Fpart, F);
  hipLaunchKernelGGL(k4_out, dim3(64 * 4), dim3(512), 0, stream,
                     Abuf, W2T, cbuf, nd, F, out);
}